// Round 5
// baseline (134.088 us; speedup 1.0000x reference)
//
#include <hip/hip_runtime.h>
#include <stdint.h>

#define KWORDS 128   // 4096 bits / 32 per row

// popcount-accumulate: LLVM folds add(ctpop(x), acc) -> v_bcnt_u32_b32 x, acc
__device__ __forceinline__ void xpc(int& acc, uint32_t a, uint32_t w) {
    acc = (int)__popc(a ^ w) + acc;
}

// ---------------- pack kernels ----------------
// x -> TRANSPOSED packed layout: At[ck][row][pos], ck = w>>4, pos = w&15.
// (lane-stride 64B on the GEMM side -> coalesced per-lane quad loads)
__global__ __launch_bounds__(256)
void pack_f32_t(const float* __restrict__ in, uint32_t* __restrict__ out) {
    uint32_t g = blockIdx.x * 256 + threadIdx.x;    // one 32-elem word per thread
    uint32_t r = g >> 7, w = g & 127;               // row, word-in-row
    const float4* p = (const float4*)(in + (size_t)r * 4096 + w * 32);
    uint32_t word = 0;
    #pragma unroll
    for (int q = 0; q < 8; ++q) {
        float4 v = p[q];
        word |= (v.x >= 0.0f ? 1u : 0u) << (4*q + 0);
        word |= (v.y >= 0.0f ? 1u : 0u) << (4*q + 1);
        word |= (v.z >= 0.0f ? 1u : 0u) << (4*q + 2);
        word |= (v.w >= 0.0f ? 1u : 0u) << (4*q + 3);
    }
    out[(w >> 4) * (2048 * 16) + r * 16 + (w & 15)] = word;
}

// weights -> row-major packed [N][128] (consumed via scalar loads)
__global__ __launch_bounds__(256)
void pack_i32_k(const int* __restrict__ in, uint32_t* __restrict__ out) {
    size_t t = (size_t)blockIdx.x * 256 + threadIdx.x;
    const int4* p = (const int4*)(in + t * 32);
    uint32_t w = 0;
    #pragma unroll
    for (int q = 0; q < 8; ++q) {
        int4 v = p[q];   // values in {0,1}
        w |= (uint32_t)(v.x & 1) << (4*q + 0);
        w |= (uint32_t)(v.y & 1) << (4*q + 1);
        w |= (uint32_t)(v.z & 1) << (4*q + 2);
        w |= (uint32_t)(v.w & 1) << (4*q + 3);
    }
    out[t] = w;
}

// ---------------- layer 1: popcount GEMM, scalar-W, no LDS ----------------
// wave lanes = 64 consecutive rows; each lane owns 32 consecutive cols.
// A chunk (16 words) lives in VGPRs; W quads come from SGPRs (wave-uniform).
// Emits one packed activation word per lane into transposed layout Ot[ck][row][pos].
__global__ __launch_bounds__(256, 4)
void bnn_l1(const uint32_t* __restrict__ At,   // [8][2048][16]
            const uint32_t* __restrict__ W,    // [4096][128]
            const int* __restrict__ thr_ptr,
            uint32_t* __restrict__ Ot)         // [8][2048][16]
{
    const int row = blockIdx.y * 256 + threadIdx.x;   // grid.y = 8
    const int ct  = blockIdx.x;                        // grid.x = 128 (32 cols each)
    const int limit = 4096 - *thr_ptr;                 // bit = (mismatches <= limit)

    int acc[32];
    #pragma unroll
    for (int n = 0; n < 32; ++n) acc[n] = 0;

    #pragma unroll 1
    for (int ck = 0; ck < 8; ++ck) {
        const uint32_t* ap = At + ck * (2048 * 16) + row * 16;
        uint4 a0 = *(const uint4*)(ap + 0);
        uint4 a1 = *(const uint4*)(ap + 4);
        uint4 a2 = *(const uint4*)(ap + 8);
        uint4 a3 = *(const uint4*)(ap + 12);
        const uint32_t* wbase = W + (size_t)(ct * 32) * KWORDS + ck * 16;
        #pragma unroll
        for (int n = 0; n < 32; ++n) {
            const uint4* wp = (const uint4*)(wbase + (size_t)n * KWORDS);
            uint4 w0 = wp[0], w1 = wp[1], w2 = wp[2], w3 = wp[3];
            xpc(acc[n], a0.x, w0.x); xpc(acc[n], a0.y, w0.y);
            xpc(acc[n], a0.z, w0.z); xpc(acc[n], a0.w, w0.w);
            xpc(acc[n], a1.x, w1.x); xpc(acc[n], a1.y, w1.y);
            xpc(acc[n], a1.z, w1.z); xpc(acc[n], a1.w, w1.w);
            xpc(acc[n], a2.x, w2.x); xpc(acc[n], a2.y, w2.y);
            xpc(acc[n], a2.z, w2.z); xpc(acc[n], a2.w, w2.w);
            xpc(acc[n], a3.x, w3.x); xpc(acc[n], a3.y, w3.y);
            xpc(acc[n], a3.z, w3.z); xpc(acc[n], a3.w, w3.w);
        }
    }

    uint32_t word = 0;
    #pragma unroll
    for (int n = 0; n < 32; ++n)
        word |= (uint32_t)(acc[n] <= limit) << n;
    Ot[(ct >> 4) * (2048 * 16) + row * 16 + (ct & 15)] = word;
}

// ---------------- layer 2: same structure, 8 cols/lane, int32 out ----------
__global__ __launch_bounds__(256, 4)
void bnn_l2(const uint32_t* __restrict__ At,   // [8][2048][16] (packed act)
            const uint32_t* __restrict__ W,    // [1024][128]
            int* __restrict__ out)             // [2048][1024]
{
    const int row = blockIdx.y * 256 + threadIdx.x;   // grid.y = 8
    const int ct  = blockIdx.x;                        // grid.x = 128 (8 cols each)

    int acc[8];
    #pragma unroll
    for (int n = 0; n < 8; ++n) acc[n] = 0;

    #pragma unroll 1
    for (int ck = 0; ck < 8; ++ck) {
        const uint32_t* ap = At + ck * (2048 * 16) + row * 16;
        uint4 a0 = *(const uint4*)(ap + 0);
        uint4 a1 = *(const uint4*)(ap + 4);
        uint4 a2 = *(const uint4*)(ap + 8);
        uint4 a3 = *(const uint4*)(ap + 12);
        const uint32_t* wbase = W + (size_t)(ct * 8) * KWORDS + ck * 16;
        #pragma unroll
        for (int n = 0; n < 8; ++n) {
            const uint4* wp = (const uint4*)(wbase + (size_t)n * KWORDS);
            uint4 w0 = wp[0], w1 = wp[1], w2 = wp[2], w3 = wp[3];
            xpc(acc[n], a0.x, w0.x); xpc(acc[n], a0.y, w0.y);
            xpc(acc[n], a0.z, w0.z); xpc(acc[n], a0.w, w0.w);
            xpc(acc[n], a1.x, w1.x); xpc(acc[n], a1.y, w1.y);
            xpc(acc[n], a1.z, w1.z); xpc(acc[n], a1.w, w1.w);
            xpc(acc[n], a2.x, w2.x); xpc(acc[n], a2.y, w2.y);
            xpc(acc[n], a2.z, w2.z); xpc(acc[n], a2.w, w2.w);
            xpc(acc[n], a3.x, w3.x); xpc(acc[n], a3.y, w3.y);
            xpc(acc[n], a3.z, w3.z); xpc(acc[n], a3.w, w3.w);
        }
    }

    int4 o0, o1;
    o0.x = 4096 - acc[0]; o0.y = 4096 - acc[1]; o0.z = 4096 - acc[2]; o0.w = 4096 - acc[3];
    o1.x = 4096 - acc[4]; o1.y = 4096 - acc[5]; o1.z = 4096 - acc[6]; o1.w = 4096 - acc[7];
    int4* op = (int4*)(out + (size_t)row * 1024 + ct * 8);
    op[0] = o0;
    op[1] = o1;
}

extern "C" void kernel_launch(void* const* d_in, const int* in_sizes, int n_in,
                              void* d_out, int out_size, void* d_ws, size_t ws_size,
                              hipStream_t stream) {
    const float* x   = (const float*)d_in[0];
    const int*   w1  = (const int*)d_in[1];
    const int*   w2  = (const int*)d_in[2];
    const int*   thr = (const int*)d_in[3];
    int* out = (int*)d_out;

    const int B = 2048, IN = 4096, H = 4096, OUT = 1024;

    uint8_t* ws = (uint8_t*)d_ws;
    uint32_t* xpack_t = (uint32_t*)(ws);                 // [8][2048][16] = 1.0 MB
    uint32_t* w1pack  = (uint32_t*)(ws + (1u << 20));    // [4096][128]  = 2.0 MB
    uint32_t* w2pack  = (uint32_t*)(ws + (3u << 20));    // [1024][128]  = 0.5 MB
    uint32_t* actpk_t = (uint32_t*)(ws + (7u << 19));    // [8][2048][16] = 1.0 MB

    pack_f32_t<<<B * IN  / 32 / 256, 256, 0, stream>>>(x,  xpack_t);
    pack_i32_k<<<H * IN  / 32 / 256, 256, 0, stream>>>(w1, w1pack);
    pack_i32_k<<<OUT * H / 32 / 256, 256, 0, stream>>>(w2, w2pack);

    bnn_l1<<<dim3(H / 32, B / 256), 256, 0, stream>>>(xpack_t, w1pack, thr, actpk_t);
    bnn_l2<<<dim3(OUT / 8, B / 256), 256, 0, stream>>>(actpk_t, w2pack, out);
}

// Round 6
// 113.719 us; speedup vs baseline: 1.1791x; 1.1791x over previous
//
#include <hip/hip_runtime.h>
#include <stdint.h>

typedef int v4i  __attribute__((ext_vector_type(4)));
typedef int v16i __attribute__((ext_vector_type(16)));

// direct global->LDS DMA, 16B per lane; LDS dest is wave-uniform base + lane*16
__device__ __forceinline__ void gload_lds16(const void* g, void* l) {
    __builtin_amdgcn_global_load_lds(
        (const __attribute__((address_space(1))) void*)g,
        (__attribute__((address_space(3))) void*)l,
        16, 0, 0);
}

// ============================ MFMA i8 path ============================
// Fragment layout for v_mfma_i32_32x32x32_i8 operands, materialized in global:
//   F[dim32_block][k_chunk(128)][lane(64)][16 bytes]
//   lane = (dim&31) + 32*((k>>4)&1), byte = k&15  (dim = row for A, col for B)
// Values are +1/-1 (i8).  dot_pm = #eq - #neq  =>  matches = (4096 + dot_pm)/2.

// pack: one block per row (4096 elems = 256 threads x 16)
__global__ __launch_bounds__(256)
void pack_f32_pm1(const float* __restrict__ in, int8_t* __restrict__ F) {
    const int r = blockIdx.x, t = threadIdx.x;
    const float4* p = (const float4*)(in + (size_t)r * 4096 + t * 16);
    uint32_t d[4];
    #pragma unroll
    for (int q = 0; q < 4; ++q) {
        float4 v = p[q];
        d[q] =  (v.x >= 0.0f ? 1u : 0xFFu)
             | ((v.y >= 0.0f ? 1u : 0xFFu) << 8)
             | ((v.z >= 0.0f ? 1u : 0xFFu) << 16)
             | ((v.w >= 0.0f ? 1u : 0xFFu) << 24);
    }
    size_t byte = ((size_t)(r >> 5) * 128 + (t >> 1)) * 1024
                + (size_t)((r & 31) + 32 * (t & 1)) * 16;
    uint4 val; val.x = d[0]; val.y = d[1]; val.z = d[2]; val.w = d[3];
    *(uint4*)(F + byte) = val;
}

__global__ __launch_bounds__(256)
void pack_i32_pm1(const int* __restrict__ in, int8_t* __restrict__ F) {
    const int r = blockIdx.x, t = threadIdx.x;
    const int4* p = (const int4*)(in + (size_t)r * 4096 + t * 16);
    uint32_t d[4];
    #pragma unroll
    for (int q = 0; q < 4; ++q) {
        int4 v = p[q];
        d[q] =  (v.x ? 1u : 0xFFu)
             | ((v.y ? 1u : 0xFFu) << 8)
             | ((v.z ? 1u : 0xFFu) << 16)
             | ((v.w ? 1u : 0xFFu) << 24);
    }
    size_t byte = ((size_t)(r >> 5) * 128 + (t >> 1)) * 1024
                + (size_t)((r & 31) + 32 * (t & 1)) * 16;
    uint4 val; val.x = d[0]; val.y = d[1]; val.z = d[2]; val.w = d[3];
    *(uint4*)(F + byte) = val;
}

// i8 MFMA GEMM, m97 structure: 128x(64*WN) tile, 256 thr (4 waves as 2x2),
// BK=64, double-buffered LDS, global_load_lds staging, one barrier/K-tile.
// PACK_OUT: threshold -> write +-1 i8 act in A-fragment layout (layer 1).
// else:     write int32 matches (layer 2, final output).
template<int WN, bool PACK_OUT>
__global__ __launch_bounds__(256)
void bnn_mfma(const int8_t* __restrict__ Af,
              const int8_t* __restrict__ Bf,
              const int* __restrict__ thr_ptr,
              int8_t* __restrict__ actf,
              int* __restrict__ out, int Nout)
{
    constexpr int KC     = 128;            // K/32 chunks
    constexpr int NKT    = 64;             // K-tiles of BK=64
    constexpr int ASLOTS = 512;            // 4 row-blocks x 2 kc x 64 lanes
    constexpr int BSLOTS = 256 * WN;       // 2*WN col-blocks x 2 kc x 64
    constexpr int SLOTS  = ASLOTS + BSLOTS;
    constexpr int NLD    = SLOTS / 256;    // gload_lds per thread per tile

    __shared__ int8_t lds[2][SLOTS * 16];

    const int tid  = threadIdx.x;
    const int lane = tid & 63;
    const int wv   = __builtin_amdgcn_readfirstlane(tid >> 6);
    const int wr   = wv >> 1, wc = wv & 1;
    const int bm   = blockIdx.y, bn = blockIdx.x;

    // staging descriptors: slot s = wv*64 + 256*i + lane  (R,C uniform per (wv,i))
    const int8_t* gsrc[NLD];
    uint32_t ldoff[NLD];
    #pragma unroll
    for (int i = 0; i < NLD; ++i) {
        int sbase = wv * 64 + 256 * i;
        ldoff[i] = (uint32_t)sbase * 16;
        const int8_t* base;
        if (sbase < ASLOTS) {
            int R = sbase >> 7, C = (sbase >> 6) & 1;
            base = Af + ((size_t)(bm * 4 + R) * KC + C) * 1024;
        } else {
            int s = sbase - ASLOTS;
            int R = s >> 7, C = (s >> 6) & 1;
            base = Bf + ((size_t)(bn * 2 * WN + R) * KC + C) * 1024;
        }
        gsrc[i] = base + lane * 16;
    }

    auto stage = [&](int buf) {
        #pragma unroll
        for (int i = 0; i < NLD; ++i) {
            gload_lds16(gsrc[i], &lds[buf][ldoff[i]]);
            gsrc[i] += 2048;               // next K-tile: C += 2
        }
    };

    v16i acc[2][WN];
    #pragma unroll
    for (int i = 0; i < 2; ++i)
        #pragma unroll
        for (int j = 0; j < WN; ++j) acc[i][j] = {};

    stage(0);
    __syncthreads();

    int cur = 0;
    #pragma unroll 1
    for (int kt = 0; kt < NKT; ++kt) {
        if (kt + 1 < NKT) stage(cur ^ 1);
        const int8_t* Al = lds[cur];
        const int8_t* Bl = lds[cur] + ASLOTS * 16;
        #pragma unroll
        for (int kc = 0; kc < 2; ++kc) {
            v4i af[2], bf[WN];
            #pragma unroll
            for (int i = 0; i < 2; ++i)
                af[i] = *(const v4i*)(Al + (((wr * 2 + i) * 128 + kc * 64 + lane) * 16));
            #pragma unroll
            for (int j = 0; j < WN; ++j)
                bf[j] = *(const v4i*)(Bl + (((wc * WN + j) * 128 + kc * 64 + lane) * 16));
            #pragma unroll
            for (int i = 0; i < 2; ++i)
                #pragma unroll
                for (int j = 0; j < WN; ++j)
                    acc[i][j] = __builtin_amdgcn_mfma_i32_32x32x32_i8(af[i], bf[j], acc[i][j], 0, 0, 0);
        }
        __syncthreads();
        cur ^= 1;
    }

    // C/D layout (verified, dtype-independent): col = lane&31,
    // row = (reg&3) + 8*(reg>>2) + 4*(lane>>5)
    const int row0 = bm * 128 + wr * 64;
    if constexpr (PACK_OUT) {
        const int thr = *thr_ptr;
        #pragma unroll
        for (int i = 0; i < 2; ++i)
            #pragma unroll
            for (int j = 0; j < WN; ++j) {
                int gc = bn * 128 + wc * 64 + j * 32 + (lane & 31);
                size_t colpart = (size_t)(gc >> 5) * 1024
                               + (size_t)((gc >> 4) & 1) * 512 + (gc & 15);
                #pragma unroll
                for (int reg = 0; reg < 16; ++reg) {
                    int row = (reg & 3) + 8 * (reg >> 2) + 4 * (lane >> 5);
                    int gr  = row0 + i * 32 + row;
                    int match = (4096 + acc[i][j][reg]) >> 1;
                    int8_t v = (match >= thr) ? (int8_t)1 : (int8_t)-1;
                    actf[(size_t)(gr >> 5) * (KC * 1024) + colpart + (size_t)(gr & 31) * 16] = v;
                }
            }
    } else {
        #pragma unroll
        for (int i = 0; i < 2; ++i)
            #pragma unroll
            for (int j = 0; j < WN; ++j) {
                int gc = bn * (64 * WN) + wc * (32 * WN) + j * 32 + (lane & 31);
                #pragma unroll
                for (int reg = 0; reg < 16; ++reg) {
                    int row = (reg & 3) + 8 * (reg >> 2) + 4 * (lane >> 5);
                    int gr  = row0 + i * 32 + row;
                    out[(size_t)gr * Nout + gc] = (4096 + acc[i][j][reg]) >> 1;
                }
            }
    }
}

// ===================== fallback path (round-5, proven) =====================
#define KWORDS 128
__device__ __forceinline__ void xpc(int& acc, uint32_t a, uint32_t w) {
    acc = (int)__popc(a ^ w) + acc;
}

__global__ __launch_bounds__(256)
void pack_f32_t(const float* __restrict__ in, uint32_t* __restrict__ out) {
    uint32_t g = blockIdx.x * 256 + threadIdx.x;
    uint32_t r = g >> 7, w = g & 127;
    const float4* p = (const float4*)(in + (size_t)r * 4096 + w * 32);
    uint32_t word = 0;
    #pragma unroll
    for (int q = 0; q < 8; ++q) {
        float4 v = p[q];
        word |= (v.x >= 0.0f ? 1u : 0u) << (4*q + 0);
        word |= (v.y >= 0.0f ? 1u : 0u) << (4*q + 1);
        word |= (v.z >= 0.0f ? 1u : 0u) << (4*q + 2);
        word |= (v.w >= 0.0f ? 1u : 0u) << (4*q + 3);
    }
    out[(w >> 4) * (2048 * 16) + r * 16 + (w & 15)] = word;
}

__global__ __launch_bounds__(256)
void pack_i32_k(const int* __restrict__ in, uint32_t* __restrict__ out) {
    size_t t = (size_t)blockIdx.x * 256 + threadIdx.x;
    const int4* p = (const int4*)(in + t * 32);
    uint32_t w = 0;
    #pragma unroll
    for (int q = 0; q < 8; ++q) {
        int4 v = p[q];
        w |= (uint32_t)(v.x & 1) << (4*q + 0);
        w |= (uint32_t)(v.y & 1) << (4*q + 1);
        w |= (uint32_t)(v.z & 1) << (4*q + 2);
        w |= (uint32_t)(v.w & 1) << (4*q + 3);
    }
    out[t] = w;
}

__global__ __launch_bounds__(256, 4)
void bnn_l1(const uint32_t* __restrict__ At, const uint32_t* __restrict__ W,
            const int* __restrict__ thr_ptr, uint32_t* __restrict__ Ot)
{
    const int row = blockIdx.y * 256 + threadIdx.x;
    const int ct  = blockIdx.x;
    const int limit = 4096 - *thr_ptr;
    int acc[32];
    #pragma unroll
    for (int n = 0; n < 32; ++n) acc[n] = 0;
    #pragma unroll 1
    for (int ck = 0; ck < 8; ++ck) {
        const uint32_t* ap = At + ck * (2048 * 16) + row * 16;
        uint4 a0 = *(const uint4*)(ap + 0);
        uint4 a1 = *(const uint4*)(ap + 4);
        uint4 a2 = *(const uint4*)(ap + 8);
        uint4 a3 = *(const uint4*)(ap + 12);
        const uint32_t* wbase = W + (size_t)(ct * 32) * KWORDS + ck * 16;
        #pragma unroll
        for (int n = 0; n < 32; ++n) {
            const uint4* wp = (const uint4*)(wbase + (size_t)n * KWORDS);
            uint4 w0 = wp[0], w1 = wp[1], w2 = wp[2], w3 = wp[3];
            xpc(acc[n], a0.x, w0.x); xpc(acc[n], a0.y, w0.y);
            xpc(acc[n], a0.z, w0.z); xpc(acc[n], a0.w, w0.w);
            xpc(acc[n], a1.x, w1.x); xpc(acc[n], a1.y, w1.y);
            xpc(acc[n], a1.z, w1.z); xpc(acc[n], a1.w, w1.w);
            xpc(acc[n], a2.x, w2.x); xpc(acc[n], a2.y, w2.y);
            xpc(acc[n], a2.z, w2.z); xpc(acc[n], a2.w, w2.w);
            xpc(acc[n], a3.x, w3.x); xpc(acc[n], a3.y, w3.y);
            xpc(acc[n], a3.z, w3.z); xpc(acc[n], a3.w, w3.w);
        }
    }
    uint32_t word = 0;
    #pragma unroll
    for (int n = 0; n < 32; ++n)
        word |= (uint32_t)(acc[n] <= limit) << n;
    Ot[(ct >> 4) * (2048 * 16) + row * 16 + (ct & 15)] = word;
}

__global__ __launch_bounds__(256, 4)
void bnn_l2(const uint32_t* __restrict__ At, const uint32_t* __restrict__ W,
            int* __restrict__ out)
{
    const int row = blockIdx.y * 256 + threadIdx.x;
    const int ct  = blockIdx.x;
    int acc[8];
    #pragma unroll
    for (int n = 0; n < 8; ++n) acc[n] = 0;
    #pragma unroll 1
    for (int ck = 0; ck < 8; ++ck) {
        const uint32_t* ap = At + ck * (2048 * 16) + row * 16;
        uint4 a0 = *(const uint4*)(ap + 0);
        uint4 a1 = *(const uint4*)(ap + 4);
        uint4 a2 = *(const uint4*)(ap + 8);
        uint4 a3 = *(const uint4*)(ap + 12);
        const uint32_t* wbase = W + (size_t)(ct * 8) * KWORDS + ck * 16;
        #pragma unroll
        for (int n = 0; n < 8; ++n) {
            const uint4* wp = (const uint4*)(wbase + (size_t)n * KWORDS);
            uint4 w0 = wp[0], w1 = wp[1], w2 = wp[2], w3 = wp[3];
            xpc(acc[n], a0.x, w0.x); xpc(acc[n], a0.y, w0.y);
            xpc(acc[n], a0.z, w0.z); xpc(acc[n], a0.w, w0.w);
            xpc(acc[n], a1.x, w1.x); xpc(acc[n], a1.y, w1.y);
            xpc(acc[n], a1.z, w1.z); xpc(acc[n], a1.w, w1.w);
            xpc(acc[n], a2.x, w2.x); xpc(acc[n], a2.y, w2.y);
            xpc(acc[n], a2.z, w2.z); xpc(acc[n], a2.w, w2.w);
            xpc(acc[n], a3.x, w3.x); xpc(acc[n], a3.y, w3.y);
            xpc(acc[n], a3.z, w3.z); xpc(acc[n], a3.w, w3.w);
        }
    }
    int4 o0, o1;
    o0.x = 4096 - acc[0]; o0.y = 4096 - acc[1]; o0.z = 4096 - acc[2]; o0.w = 4096 - acc[3];
    o1.x = 4096 - acc[4]; o1.y = 4096 - acc[5]; o1.z = 4096 - acc[6]; o1.w = 4096 - acc[7];
    int4* op = (int4*)(out + (size_t)row * 1024 + ct * 8);
    op[0] = o0;
    op[1] = o1;
}

// ============================ launcher ============================
extern "C" void kernel_launch(void* const* d_in, const int* in_sizes, int n_in,
                              void* d_out, int out_size, void* d_ws, size_t ws_size,
                              hipStream_t stream) {
    const float* x   = (const float*)d_in[0];
    const int*   w1  = (const int*)d_in[1];
    const int*   w2  = (const int*)d_in[2];
    const int*   thr = (const int*)d_in[3];
    int* out = (int*)d_out;

    const int B = 2048, IN = 4096, H = 4096, OUT = 1024;
    uint8_t* ws = (uint8_t*)d_ws;

    if (ws_size >= (size_t)36 * 1024 * 1024) {
        // MFMA i8 path: Af 8MB | W1f 16MB | W2f 4MB | Act 8MB
        int8_t* Af  = (int8_t*)(ws);
        int8_t* W1f = (int8_t*)(ws + ((size_t)8  << 20));
        int8_t* W2f = (int8_t*)(ws + ((size_t)24 << 20));
        int8_t* Act = (int8_t*)(ws + ((size_t)28 << 20));

        pack_f32_pm1<<<B,   256, 0, stream>>>(x,  Af);
        pack_i32_pm1<<<H,   256, 0, stream>>>(w1, W1f);
        pack_i32_pm1<<<OUT, 256, 0, stream>>>(w2, W2f);

        bnn_mfma<2, true ><<<dim3(H / 128,   B / 128), 256, 0, stream>>>(Af,  W1f, thr, Act, nullptr, 0);
        bnn_mfma<1, false><<<dim3(OUT / 64,  B / 128), 256, 0, stream>>>(Act, W2f, nullptr, nullptr, out, OUT);
    } else {
        // fallback: round-5 proven path (needs 4.5 MB)
        uint32_t* xpack_t = (uint32_t*)(ws);
        uint32_t* w1pack  = (uint32_t*)(ws + (1u << 20));
        uint32_t* w2pack  = (uint32_t*)(ws + (3u << 20));
        uint32_t* actpk_t = (uint32_t*)(ws + (7u << 19));

        pack_f32_t<<<B * IN  / 32 / 256, 256, 0, stream>>>(x,  xpack_t);
        pack_i32_k<<<H * IN  / 32 / 256, 256, 0, stream>>>(w1, w1pack);
        pack_i32_k<<<OUT * H / 32 / 256, 256, 0, stream>>>(w2, w2pack);

        bnn_l1<<<dim3(H / 32, B / 256), 256, 0, stream>>>(xpack_t, w1pack, thr, actpk_t);
        bnn_l2<<<dim3(OUT / 8, B / 256), 256, 0, stream>>>(actpk_t, w2pack, out);
    }
}

// Round 7
// 96.331 us; speedup vs baseline: 1.3920x; 1.1805x over previous
//
#include <hip/hip_runtime.h>
#include <stdint.h>

typedef int v4i  __attribute__((ext_vector_type(4)));
typedef int v16i __attribute__((ext_vector_type(16)));

// direct global->LDS DMA, 16B per lane; LDS dest is wave-uniform base + lane*16
__device__ __forceinline__ void gload_lds16(const void* g, void* l) {
    __builtin_amdgcn_global_load_lds(
        (const __attribute__((address_space(1))) void*)g,
        (__attribute__((address_space(3))) void*)l, 16, 0, 0);
}

// ================= packing: fragment layout [dimblk][kc][lane][16B] =========
// lane = (dim&31) + 32*khalf, byte = k&15  (k_local = khalf*16 + byte within kc's 32)
// Values +1/-1 i8.  Per block: 32 dims x 1024 k strip; LDS transpose; coalesced
// strip reads AND contiguous 1KB slab writes.
template<typename T, bool ISFLOAT>
__global__ __launch_bounds__(256)
void pack_frag(const T* __restrict__ in, int8_t* __restrict__ F, int K) {
    __shared__ int8_t lbuf[32 * 1040];          // stride 1040 B (bank-spread)
    const int t  = threadIdx.x;
    const int db = blockIdx.y;                  // dim block (32 rows)
    const int c0 = blockIdx.x * 1024;           // k strip

    #pragma unroll 4
    for (int r = 0; r < 32; ++r) {
        uint32_t b;
        if constexpr (ISFLOAT) {
            const float4 v = *(const float4*)(in + (size_t)(db * 32 + r) * K + c0 + t * 4);
            b =  (v.x >= 0.0f ? 0x01u : 0xFFu)
              | ((v.y >= 0.0f ? 0x01u : 0xFFu) << 8)
              | ((v.z >= 0.0f ? 0x01u : 0xFFu) << 16)
              | ((v.w >= 0.0f ? 0x01u : 0xFFu) << 24);
        } else {
            const int4 v = *(const int4*)(in + (size_t)(db * 32 + r) * K + c0 + t * 4);
            b =  (v.x ? 0x01u : 0xFFu)
              | ((v.y ? 0x01u : 0xFFu) << 8)
              | ((v.z ? 0x01u : 0xFFu) << 16)
              | ((v.w ? 0x01u : 0xFFu) << 24);
        }
        *(uint32_t*)(lbuf + r * 1040 + t * 4) = b;
    }
    __syncthreads();

    const int s  = t >> 3;                      // kc slab within strip: 0..31
    const int l0 = (t & 7) * 8;                 // 8 lanes per thread
    const int KC = K >> 5;
    int8_t* dst = F + ((size_t)db * KC + blockIdx.x * 32 + s) * 1024 + l0 * 16;
    #pragma unroll
    for (int li = 0; li < 8; ++li) {
        int l = l0 + li;
        uint4 v = *(const uint4*)(lbuf + (l & 31) * 1040 + s * 32 + (l >> 5) * 16);
        *(uint4*)(dst + li * 16) = v;
    }
}

// ================= popcount GEMM via i8 MFMA ================================
// C[b,n]: matches = (4096 + dot_pm)/2, dot over +-1 encodings.
// Block 128 x (64*WN), 4 waves (2x2), wave-tile 64 x (32*WN), BK=64.
// 3-deep LDS pipeline, counted vmcnt (T3+T4), raw s_barrier, XCD swizzle (T1).
template<int WN, bool PACK_OUT>
__global__ __launch_bounds__(256, 1)
void bnn_mfma(const int8_t* __restrict__ Af,
              const int8_t* __restrict__ Bf,
              const int* __restrict__ thr_ptr,
              int8_t* __restrict__ actf,
              int* __restrict__ out, int Nout)
{
    constexpr int KC     = 128;                 // K/32
    constexpr int NKT    = 64;                  // K-tiles (BK=64)
    constexpr int NBB    = 2 * WN;              // B col-blocks per block
    constexpr int ASLOTS = 512;                 // 4 rowblk x 2 kc x 64
    constexpr int BSLOTS = 128 * NBB;           // NBB x 2 kc x 64
    constexpr int SLOTS  = ASLOTS + BSLOTS;
    constexpr int NLD    = SLOTS / 256;         // gloads per thread per tile
    constexpr uint32_t BUFSZ = (uint32_t)SLOTS * 16;

    __shared__ int8_t lds[3][SLOTS * 16];

    const int tid  = threadIdx.x;
    const int lane = tid & 63;
    const int wv   = tid >> 6;
    const int wr   = wv >> 1, wc = wv & 1;

    // bijective XCD swizzle: grid 256 = 16(bn) x 16(bm), nwg%8==0
    const int g   = blockIdx.x;
    const int idx = g >> 3;
    const int bn  = (g & 7) * 2 + (idx >> 4);
    const int bm  = idx & 15;

    // staging descriptors: slot s = wv*64 + 256*i + lane
    const int8_t* gsrc[NLD];
    uint32_t ldoff[NLD];
    #pragma unroll
    for (int i = 0; i < NLD; ++i) {
        int sbase = wv * 64 + 256 * i;
        ldoff[i] = (uint32_t)sbase * 16;
        const int8_t* base;
        if (sbase < ASLOTS) {
            int R = sbase >> 7, C = (sbase >> 6) & 1;
            base = Af + ((size_t)(bm * 4 + R) * KC + C) * 1024;
        } else {
            int s = sbase - ASLOTS;
            int R = s >> 7, C = (s >> 6) & 1;
            base = Bf + ((size_t)(bn * NBB + R) * KC + C) * 1024;
        }
        gsrc[i] = base + lane * 16;
    }

    auto stage = [&](int buf) {
        #pragma unroll
        for (int i = 0; i < NLD; ++i) {
            gload_lds16(gsrc[i], (int8_t*)lds + (uint32_t)buf * BUFSZ + ldoff[i]);
            gsrc[i] += 2048;                    // next K-tile (2 kc slabs)
        }
    };

    v16i acc[2][WN];
    #pragma unroll
    for (int i = 0; i < 2; ++i)
        #pragma unroll
        for (int j = 0; j < WN; ++j) acc[i][j] = {};

    stage(0);                                   // tile 0 -> buf 0
    stage(1);                                   // tile 1 -> buf 1

    int cur = 0, nxt = 2;
    #pragma unroll 1
    for (int kt = 0; kt < NKT; ++kt) {
        // counted wait: own oldest tile landed; next tile stays in flight
        if (kt < NKT - 1) {
            if constexpr (NLD == 6) asm volatile("s_waitcnt vmcnt(6)" ::: "memory");
            else                    asm volatile("s_waitcnt vmcnt(3)" ::: "memory");
        } else {
            asm volatile("s_waitcnt vmcnt(0)" ::: "memory");
        }
        __builtin_amdgcn_sched_barrier(0);
        __builtin_amdgcn_s_barrier();
        __builtin_amdgcn_sched_barrier(0);

        if (kt < NKT - 2) {                     // issue-early (T14)
            stage(nxt);
            nxt = (nxt == 2) ? 0 : nxt + 1;
        }

        const int8_t* Al = lds[cur];
        const int8_t* Bl = lds[cur] + ASLOTS * 16;
        #pragma unroll
        for (int kc = 0; kc < 2; ++kc) {
            v4i af[2], bf[WN];
            #pragma unroll
            for (int i = 0; i < 2; ++i)
                af[i] = *(const v4i*)(Al + (((wr * 2 + i) * 2 + kc) * 64 + lane) * 16);
            #pragma unroll
            for (int j = 0; j < WN; ++j)
                bf[j] = *(const v4i*)(Bl + (((wc * WN + j) * 2 + kc) * 64 + lane) * 16);
            #pragma unroll
            for (int i = 0; i < 2; ++i)
                #pragma unroll
                for (int j = 0; j < WN; ++j)
                    acc[i][j] = __builtin_amdgcn_mfma_i32_32x32x32_i8(af[i], bf[j], acc[i][j], 0, 0, 0);
        }
        cur = (cur == 2) ? 0 : cur + 1;
    }

    if constexpr (PACK_OUT) {
        // threshold -> +-1 bytes -> LDS transpose -> contiguous A-frag slabs
        __syncthreads();
        const int thr = *thr_ptr;
        int8_t* bits = (int8_t*)lds;            // [128][272]
        #pragma unroll
        for (int i = 0; i < 2; ++i)
            #pragma unroll
            for (int j = 0; j < WN; ++j) {
                int dimb = wr * 64 + i * 32 + 4 * (lane >> 5);
                int gcl  = wc * (32 * WN) + j * 32 + (lane & 31);
                #pragma unroll
                for (int reg = 0; reg < 16; ++reg) {
                    int dl = dimb + (reg & 3) + 8 * (reg >> 2);
                    int match = (4096 + acc[i][j][reg]) >> 1;
                    bits[dl * 272 + gcl] = (match >= thr) ? (int8_t)1 : (int8_t)-1;
                }
            }
        __syncthreads();
        const int s    = tid >> 3;              // 32 slabs: 4 dimblk x 8 kc
        const int dblk = s >> 3, kcl = s & 7;
        const int l0   = (tid & 7) * 8;
        int8_t* dst = actf + ((size_t)(bm * 4 + dblk) * KC + bn * 8 + kcl) * 1024 + l0 * 16;
        #pragma unroll
        for (int li = 0; li < 8; ++li) {
            int l = l0 + li;
            uint4 v = *(const uint4*)(bits + (dblk * 32 + (l & 31)) * 272
                                           + kcl * 32 + (l >> 5) * 16);
            *(uint4*)(dst + li * 16) = v;
        }
    } else {
        #pragma unroll
        for (int i = 0; i < 2; ++i)
            #pragma unroll
            for (int j = 0; j < WN; ++j) {
                int gc = bn * (64 * WN) + wc * (32 * WN) + j * 32 + (lane & 31);
                #pragma unroll
                for (int reg = 0; reg < 16; ++reg) {
                    int gr = bm * 128 + wr * 64 + i * 32
                           + (reg & 3) + 8 * (reg >> 2) + 4 * (lane >> 5);
                    out[(size_t)gr * Nout + gc] = (4096 + acc[i][j][reg]) >> 1;
                }
            }
    }
}

// ============================ launcher ============================
extern "C" void kernel_launch(void* const* d_in, const int* in_sizes, int n_in,
                              void* d_out, int out_size, void* d_ws, size_t ws_size,
                              hipStream_t stream) {
    const float* x   = (const float*)d_in[0];
    const int*   w1  = (const int*)d_in[1];
    const int*   w2  = (const int*)d_in[2];
    const int*   thr = (const int*)d_in[3];
    int* out = (int*)d_out;

    const int B = 2048, IN = 4096, H = 4096, OUT = 1024;
    uint8_t* ws = (uint8_t*)d_ws;

    // Af 8MB | W1f 16MB | W2f 4MB | Act 8MB  (ws_size >= 36MB verified round 6)
    int8_t* Af  = (int8_t*)(ws);
    int8_t* W1f = (int8_t*)(ws + ((size_t)8  << 20));
    int8_t* W2f = (int8_t*)(ws + ((size_t)24 << 20));
    int8_t* Act = (int8_t*)(ws + ((size_t)28 << 20));

    pack_frag<float, true ><<<dim3(IN / 1024, B   / 32), 256, 0, stream>>>(x,  Af,  IN);
    pack_frag<int,   false><<<dim3(IN / 1024, H   / 32), 256, 0, stream>>>(w1, W1f, IN);
    pack_frag<int,   false><<<dim3(H  / 1024, OUT / 32), 256, 0, stream>>>(w2, W2f, H);

    bnn_mfma<4, true ><<<256, 256, 0, stream>>>(Af,  W1f, thr, Act, nullptr, 0);   // 128x256 tiles
    bnn_mfma<1, false><<<256, 256, 0, stream>>>(Act, W2f, nullptr, nullptr, out, OUT); // 128x64 tiles
}

// Round 9
// 92.146 us; speedup vs baseline: 1.4552x; 1.0454x over previous
//
#include <hip/hip_runtime.h>
#include <stdint.h>

typedef int v4i  __attribute__((ext_vector_type(4)));
typedef int v16i __attribute__((ext_vector_type(16)));

// direct global->LDS DMA, 16B per lane; LDS dest is wave-uniform base + lane*16
__device__ __forceinline__ void gload_lds16(const void* g, void* l) {
    __builtin_amdgcn_global_load_lds(
        (const __attribute__((address_space(1))) void*)g,
        (__attribute__((address_space(3))) void*)l, 16, 0, 0);
}

// ================= packing: fragment layout [dimblk][kc][lane][16B] =========
// lane = (dim&31) + 32*khalf, byte = k&15. Values +1/-1 i8.
// 512 threads: 16 read-iters into LDS, then 32 slab-writes of 1KB contiguous.
template<typename T, bool ISFLOAT>
__global__ __launch_bounds__(512)
void pack_frag(const T* __restrict__ in, int8_t* __restrict__ F, int K) {
    __shared__ int8_t lbuf[32 * 1040];
    const int t  = threadIdx.x;
    const int db = blockIdx.y;                  // dim block (32 rows)
    const int c0 = blockIdx.x << 10;            // k strip (1024 cols)

    #pragma unroll
    for (int p = 0; p < 16; ++p) {
        int idx = p * 512 + t;
        int row = idx >> 8, c4 = idx & 255;     // c4: float4/int4 slot in row
        uint32_t b;
        if constexpr (ISFLOAT) {
            const float4 v = *(const float4*)(in + (size_t)(db * 32 + row) * K + c0 + c4 * 4);
            b =  (v.x >= 0.0f ? 0x01u : 0xFFu)
              | ((v.y >= 0.0f ? 0x01u : 0xFFu) << 8)
              | ((v.z >= 0.0f ? 0x01u : 0xFFu) << 16)
              | ((v.w >= 0.0f ? 0x01u : 0xFFu) << 24);
        } else {
            const int4 v = *(const int4*)(in + (size_t)(db * 32 + row) * K + c0 + c4 * 4);
            b =  (v.x ? 0x01u : 0xFFu)
              | ((v.y ? 0x01u : 0xFFu) << 8)
              | ((v.z ? 0x01u : 0xFFu) << 16)
              | ((v.w ? 0x01u : 0xFFu) << 24);
        }
        *(uint32_t*)(lbuf + row * 1040 + c4 * 4) = b;
    }
    __syncthreads();

    const int s  = t >> 4;                      // slab 0..31 (kc within strip)
    const int l0 = (t & 15) * 4;                // 4 lanes per thread
    const int KC = K >> 5;
    int8_t* dst = F + ((size_t)db * KC + blockIdx.x * 32 + s) * 1024;
    #pragma unroll
    for (int li = 0; li < 4; ++li) {
        int l = l0 + li;
        uint4 v = *(const uint4*)(lbuf + (l & 31) * 1040 + s * 32 + (l >> 5) * 16);
        *(uint4*)(dst + l * 16) = v;
    }
}

// ================= layer 1: i8 MFMA GEMM, m201-style phase interleave =======
// Tile 128x256, 512 thr = 8 waves (2 wr x 4 wc), wave-tile 64x64, acc[2][2].
// BK=64 (2 kc-phases/kt), 3-deep LDS ring (3 x 24KB), counted vmcnt(3)/kt.
// Ring: kt reads buf(kt%3); kt stages kt+2 into buf((kt+2)%3) == bo - BUFSZ.
__global__ __launch_bounds__(512, 2)
void bnn_l1_8w(const int8_t* __restrict__ Af,   // [64][128][64][16]
               const int8_t* __restrict__ Bf,   // [128][128][64][16]
               const int* __restrict__ thr_ptr,
               int8_t* __restrict__ actf)       // [64][128][64][16]
{
    constexpr int KC  = 128;
    constexpr int NKT = 64;
    constexpr uint32_t BUFSZ = 24576;           // (4 A + 8 B blks) x 2 kc x 1KB

    __shared__ int8_t lds[3 * 24576];           // 72KB (also reused as bits)

    const int tid  = threadIdx.x;
    const int lane = tid & 63;
    const int wv   = tid >> 6;
    const int wr   = wv >> 2, wc = wv & 3;

    // bijective XCD swizzle: grid 256 = 16(bn) x 16(bm)
    const int g   = blockIdx.x;
    const int idx = g >> 3;
    const int bn  = (g & 7) * 2 + (idx >> 4);
    const int bm  = idx & 15;

    // staging: 3 gloads/thread/kt; slot = c*512 + tid
    const int8_t* gsrc[3];
    uint32_t loff[3];
    #pragma unroll
    for (int c = 0; c < 3; ++c) {
        int s = c * 512 + tid;
        if (s < 512) {                          // A: rowblk, kc, lane
            int R = s >> 7, kk = (s >> 6) & 1, ln = s & 63;
            gsrc[c] = Af + ((size_t)(bm * 4 + R) * KC + kk) * 1024 + ln * 16;
            loff[c] = (uint32_t)s * 16;
        } else {                                // B: colblk, kc, lane
            int s2 = s - 512;
            int Cb = s2 >> 7, kk = (s2 >> 6) & 1, ln = s2 & 63;
            gsrc[c] = Bf + ((size_t)(bn * 8 + Cb) * KC + kk) * 1024 + ln * 16;
            loff[c] = 8192u + (uint32_t)s2 * 16;
        }
    }

    auto issue = [&](int c, uint32_t bufo) {
        gload_lds16(gsrc[c], lds + bufo + loff[c]);
        gsrc[c] += 2048;                        // next kt (2 kc slabs)
    };

    v16i acc[2][2];
    #pragma unroll
    for (int i = 0; i < 2; ++i)
        #pragma unroll
        for (int j = 0; j < 2; ++j) acc[i][j] = {};

    // prologue: kt0 -> buf0, kt1 -> buf1
    issue(0, 0); issue(1, 0); issue(2, 0);
    issue(0, BUFSZ); issue(1, BUFSZ); issue(2, BUFSZ);

    uint32_t bo = 0;                            // read buffer offset (kt%3)
    #pragma unroll 1
    for (int kt = 0; kt < NKT; ++kt) {
        // collective "buf(kt) landed": counted vmcnt + barrier
        if (kt + 1 < NKT) asm volatile("s_waitcnt vmcnt(3)" ::: "memory");
        else              asm volatile("s_waitcnt vmcnt(0)" ::: "memory");
        __builtin_amdgcn_sched_barrier(0);
        __builtin_amdgcn_s_barrier();
        __builtin_amdgcn_sched_barrier(0);

        // stage target for kt+2: buf((kt+2)%3) = bo - BUFSZ (mod 3*BUFSZ).
        // (That buffer's reads finished before this kt's lead barrier.)
        const uint32_t sbo = (bo >= BUFSZ) ? (bo - BUFSZ) : (2 * BUFSZ);
        const int8_t* Ab = lds + bo + wr * 4096 + lane * 16;
        const int8_t* Bb = lds + bo + 8192 + wc * 4096 + lane * 16;

        // ---- phase 0 (kc=0): reads + 2 gload issues, then MFMA cluster ----
        {
            v4i af0 = *(const v4i*)(Ab + 0);
            v4i af1 = *(const v4i*)(Ab + 2048);
            v4i bf0 = *(const v4i*)(Bb + 0);
            v4i bf1 = *(const v4i*)(Bb + 2048);
            if (kt + 2 < NKT) { issue(0, sbo); issue(1, sbo); }
            __builtin_amdgcn_s_barrier();
            asm volatile("s_waitcnt lgkmcnt(0)" ::: "memory");
            __builtin_amdgcn_sched_barrier(0);
            __builtin_amdgcn_s_setprio(1);
            acc[0][0] = __builtin_amdgcn_mfma_i32_32x32x32_i8(af0, bf0, acc[0][0], 0, 0, 0);
            acc[0][1] = __builtin_amdgcn_mfma_i32_32x32x32_i8(af0, bf1, acc[0][1], 0, 0, 0);
            acc[1][0] = __builtin_amdgcn_mfma_i32_32x32x32_i8(af1, bf0, acc[1][0], 0, 0, 0);
            acc[1][1] = __builtin_amdgcn_mfma_i32_32x32x32_i8(af1, bf1, acc[1][1], 0, 0, 0);
            __builtin_amdgcn_s_setprio(0);
            __builtin_amdgcn_sched_barrier(0);
            __builtin_amdgcn_s_barrier();
        }
        // ---- phase 1 (kc=1): reads + 1 gload issue, then MFMA cluster ----
        {
            v4i af0 = *(const v4i*)(Ab + 1024);
            v4i af1 = *(const v4i*)(Ab + 3072);
            v4i bf0 = *(const v4i*)(Bb + 1024);
            v4i bf1 = *(const v4i*)(Bb + 3072);
            if (kt + 2 < NKT) issue(2, sbo);
            __builtin_amdgcn_s_barrier();
            asm volatile("s_waitcnt lgkmcnt(0)" ::: "memory");
            __builtin_amdgcn_sched_barrier(0);
            __builtin_amdgcn_s_setprio(1);
            acc[0][0] = __builtin_amdgcn_mfma_i32_32x32x32_i8(af0, bf0, acc[0][0], 0, 0, 0);
            acc[0][1] = __builtin_amdgcn_mfma_i32_32x32x32_i8(af0, bf1, acc[0][1], 0, 0, 0);
            acc[1][0] = __builtin_amdgcn_mfma_i32_32x32x32_i8(af1, bf0, acc[1][0], 0, 0, 0);
            acc[1][1] = __builtin_amdgcn_mfma_i32_32x32x32_i8(af1, bf1, acc[1][1], 0, 0, 0);
            __builtin_amdgcn_s_setprio(0);
            __builtin_amdgcn_sched_barrier(0);
            // trailing barrier of this kt == next kt's lead barrier
        }
        bo = (bo == 2 * BUFSZ) ? 0u : bo + BUFSZ;   // advance read buffer
    }

    // ---- epilogue: threshold -> +-1 bytes -> LDS transpose -> Act slabs ----
    __syncthreads();
    const int thr = *thr_ptr;
    int8_t* bits = lds;                         // [128][272] = 34.8KB
    #pragma unroll
    for (int i = 0; i < 2; ++i)
        #pragma unroll
        for (int j = 0; j < 2; ++j) {
            int dimb = wr * 64 + i * 32 + 4 * (lane >> 5);
            int gcl  = wc * 64 + j * 32 + (lane & 31);
            #pragma unroll
            for (int reg = 0; reg < 16; ++reg) {
                int dl = dimb + (reg & 3) + 8 * (reg >> 2);
                int match = (4096 + acc[i][j][reg]) >> 1;
                bits[dl * 272 + gcl] = (match >= thr) ? (int8_t)1 : (int8_t)-1;
            }
        }
    __syncthreads();
    // 32 slabs (4 dimblk x 8 kc) x 1KB; 16 threads/slab, 4 lanes each
    const int s    = tid >> 4;
    const int dblk = s >> 3, kcl = s & 7;
    const int l0   = (tid & 15) * 4;
    int8_t* dst = actf + ((size_t)(bm * 4 + dblk) * KC + bn * 8 + kcl) * 1024;
    #pragma unroll
    for (int li = 0; li < 4; ++li) {
        int l = l0 + li;
        uint4 v = *(const uint4*)(bits + (dblk * 32 + (l & 31)) * 272
                                       + kcl * 32 + (l >> 5) * 16);
        *(uint4*)(dst + l * 16) = v;
    }
}

// ================= layer 2: round-7 proven kernel (128x64 tiles) ============
template<int WN>
__global__ __launch_bounds__(256, 1)
void bnn_mfma2(const int8_t* __restrict__ Af,
               const int8_t* __restrict__ Bf,
               int* __restrict__ out, int Nout)
{
    constexpr int KC     = 128;
    constexpr int NKT    = 64;
    constexpr int NBB    = 2 * WN;
    constexpr int ASLOTS = 512;
    constexpr int BSLOTS = 128 * NBB;
    constexpr int SLOTS  = ASLOTS + BSLOTS;
    constexpr int NLD    = SLOTS / 256;
    constexpr uint32_t BUFSZ = (uint32_t)SLOTS * 16;

    __shared__ int8_t lds[3][SLOTS * 16];

    const int tid  = threadIdx.x;
    const int lane = tid & 63;
    const int wv   = tid >> 6;
    const int wr   = wv >> 1, wc = wv & 1;

    const int g   = blockIdx.x;
    const int idx = g >> 3;
    const int bn  = (g & 7) * 2 + (idx >> 4);
    const int bm  = idx & 15;

    const int8_t* gsrc[NLD];
    uint32_t ldoff[NLD];
    #pragma unroll
    for (int i = 0; i < NLD; ++i) {
        int sbase = wv * 64 + 256 * i;
        ldoff[i] = (uint32_t)sbase * 16;
        const int8_t* base;
        if (sbase < ASLOTS) {
            int R = sbase >> 7, C = (sbase >> 6) & 1;
            base = Af + ((size_t)(bm * 4 + R) * KC + C) * 1024;
        } else {
            int s = sbase - ASLOTS;
            int R = s >> 7, C = (s >> 6) & 1;
            base = Bf + ((size_t)(bn * NBB + R) * KC + C) * 1024;
        }
        gsrc[i] = base + lane * 16;
    }

    auto stage = [&](int buf) {
        #pragma unroll
        for (int i = 0; i < NLD; ++i) {
            gload_lds16(gsrc[i], (int8_t*)lds + (uint32_t)buf * BUFSZ + ldoff[i]);
            gsrc[i] += 2048;
        }
    };

    v16i acc[2][WN];
    #pragma unroll
    for (int i = 0; i < 2; ++i)
        #pragma unroll
        for (int j = 0; j < WN; ++j) acc[i][j] = {};

    stage(0);
    stage(1);

    int cur = 0, nxt = 2;
    #pragma unroll 1
    for (int kt = 0; kt < NKT; ++kt) {
        if (kt < NKT - 1) asm volatile("s_waitcnt vmcnt(3)" ::: "memory");
        else              asm volatile("s_waitcnt vmcnt(0)" ::: "memory");
        __builtin_amdgcn_sched_barrier(0);
        __builtin_amdgcn_s_barrier();
        __builtin_amdgcn_sched_barrier(0);

        if (kt < NKT - 2) {
            stage(nxt);
            nxt = (nxt == 2) ? 0 : nxt + 1;
        }

        const int8_t* Al = lds[cur];
        const int8_t* Bl = lds[cur] + ASLOTS * 16;
        #pragma unroll
        for (int kc = 0; kc < 2; ++kc) {
            v4i af[2], bf[WN];
            #pragma unroll
            for (int i = 0; i < 2; ++i)
                af[i] = *(const v4i*)(Al + (((wr * 2 + i) * 2 + kc) * 64 + lane) * 16);
            #pragma unroll
            for (int j = 0; j < WN; ++j)
                bf[j] = *(const v4i*)(Bl + (((wc * WN + j) * 2 + kc) * 64 + lane) * 16);
            #pragma unroll
            for (int i = 0; i < 2; ++i)
                #pragma unroll
                for (int j = 0; j < WN; ++j)
                    acc[i][j] = __builtin_amdgcn_mfma_i32_32x32x32_i8(af[i], bf[j], acc[i][j], 0, 0, 0);
        }
        cur = (cur == 2) ? 0 : cur + 1;
    }

    #pragma unroll
    for (int i = 0; i < 2; ++i)
        #pragma unroll
        for (int j = 0; j < WN; ++j) {
            int gc = bn * (64 * WN) + wc * (32 * WN) + j * 32 + (lane & 31);
            #pragma unroll
            for (int reg = 0; reg < 16; ++reg) {
                int gr = bm * 128 + wr * 64 + i * 32
                       + (reg & 3) + 8 * (reg >> 2) + 4 * (lane >> 5);
                out[(size_t)gr * Nout + gc] = (4096 + acc[i][j][reg]) >> 1;
            }
        }
}

// ============================ launcher ============================
extern "C" void kernel_launch(void* const* d_in, const int* in_sizes, int n_in,
                              void* d_out, int out_size, void* d_ws, size_t ws_size,
                              hipStream_t stream) {
    const float* x   = (const float*)d_in[0];
    const int*   w1  = (const int*)d_in[1];
    const int*   w2  = (const int*)d_in[2];
    const int*   thr = (const int*)d_in[3];
    int* out = (int*)d_out;

    const int B = 2048, IN = 4096, H = 4096, OUT = 1024;
    uint8_t* ws = (uint8_t*)d_ws;

    // Af 8MB | W1f 16MB | W2f 4MB | Act 8MB
    int8_t* Af  = (int8_t*)(ws);
    int8_t* W1f = (int8_t*)(ws + ((size_t)8  << 20));
    int8_t* W2f = (int8_t*)(ws + ((size_t)24 << 20));
    int8_t* Act = (int8_t*)(ws + ((size_t)28 << 20));

    pack_frag<float, true ><<<dim3(IN / 1024, B   / 32), 512, 0, stream>>>(x,  Af,  IN);
    pack_frag<int,   false><<<dim3(IN / 1024, H   / 32), 512, 0, stream>>>(w1, W1f, IN);
    pack_frag<int,   false><<<dim3(H  / 1024, OUT / 32), 512, 0, stream>>>(w2, W2f, H);

    bnn_l1_8w<<<256, 512, 0, stream>>>(Af, W1f, thr, Act);                      // 128x256 tiles
    bnn_mfma2<1><<<256, 256, 0, stream>>>(Act, W2f, out, OUT);                  // 128x64 tiles
}

// Round 10
// 92.072 us; speedup vs baseline: 1.4563x; 1.0008x over previous
//
#include <hip/hip_runtime.h>
#include <stdint.h>

typedef int v4i  __attribute__((ext_vector_type(4)));
typedef int v16i __attribute__((ext_vector_type(16)));

// direct global->LDS DMA, 16B per lane; LDS dest is wave-uniform base + lane*16
__device__ __forceinline__ void gload_lds16(const void* g, void* l) {
    __builtin_amdgcn_global_load_lds(
        (const __attribute__((address_space(1))) void*)g,
        (__attribute__((address_space(3))) void*)l, 16, 0, 0);
}

// ================= packing: fragment layout [dimblk][kc][lane][16B] =========
// lane = (dim&31) + 32*khalf, byte = k&15. Values +1/-1 i8.
template<typename T, bool ISFLOAT>
__global__ __launch_bounds__(512)
void pack_frag(const T* __restrict__ in, int8_t* __restrict__ F, int K) {
    __shared__ int8_t lbuf[32 * 1040];
    const int t  = threadIdx.x;
    const int db = blockIdx.y;                  // dim block (32 rows)
    const int c0 = blockIdx.x << 10;            // k strip (1024 cols)

    #pragma unroll
    for (int p = 0; p < 16; ++p) {
        int idx = p * 512 + t;
        int row = idx >> 8, c4 = idx & 255;
        uint32_t b;
        if constexpr (ISFLOAT) {
            const float4 v = *(const float4*)(in + (size_t)(db * 32 + row) * K + c0 + c4 * 4);
            b =  (v.x >= 0.0f ? 0x01u : 0xFFu)
              | ((v.y >= 0.0f ? 0x01u : 0xFFu) << 8)
              | ((v.z >= 0.0f ? 0x01u : 0xFFu) << 16)
              | ((v.w >= 0.0f ? 0x01u : 0xFFu) << 24);
        } else {
            const int4 v = *(const int4*)(in + (size_t)(db * 32 + row) * K + c0 + c4 * 4);
            b =  (v.x ? 0x01u : 0xFFu)
              | ((v.y ? 0x01u : 0xFFu) << 8)
              | ((v.z ? 0x01u : 0xFFu) << 16)
              | ((v.w ? 0x01u : 0xFFu) << 24);
        }
        *(uint32_t*)(lbuf + row * 1040 + c4 * 4) = b;
    }
    __syncthreads();

    const int s  = t >> 4;                      // slab 0..31 (kc within strip)
    const int l0 = (t & 15) * 4;
    const int KC = K >> 5;
    int8_t* dst = F + ((size_t)db * KC + blockIdx.x * 32 + s) * 1024;
    #pragma unroll
    for (int li = 0; li < 4; ++li) {
        int l = l0 + li;
        uint4 v = *(const uint4*)(lbuf + (l & 31) * 1040 + s * 32 + (l >> 5) * 16);
        *(uint4*)(dst + l * 16) = v;
    }
}

// ================= layer 1: A-in-regs, B-in-LDS-ring, 1 barrier/kt ==========
// Tile 128x128, 256 thr = 4 waves (2 wr x 2 wc), wave-tile 64x64, acc[2][2].
// A frags: global->VGPR, double-banked, issued 1 kt ahead.
// B frags: gload_lds 3-deep ring (3 x 8KB), counted vmcnt(2), 1 s_barrier/kt.
// Grid 512 = 2 blocks/CU: second block fills the first's barrier stalls.
__global__ __launch_bounds__(256, 2)
void bnn_l1_areg(const int8_t* __restrict__ Af,   // [64][128][64][16]
                 const int8_t* __restrict__ Bf,   // [128][128][64][16]
                 const int* __restrict__ thr_ptr,
                 int8_t* __restrict__ actf)       // [64][128][64][16]
{
    constexpr int KC  = 128;
    constexpr int NKT = 64;
    constexpr uint32_t BUFSZ = 8192;            // 4 colblk x 2 kc x 1KB

    __shared__ int8_t lds[3 * 8192];            // 24KB ring; reused as bits (18KB)

    const int tid  = threadIdx.x;
    const int lane = tid & 63;
    const int wv   = tid >> 6;                  // 0..3
    const int wr   = wv >> 1, wc = wv & 1;

    // bijective XCD swizzle: 512 = 8 xcd-chunks x (4 bn x 16 bm)
    const int g   = blockIdx.x;
    const int idx = g >> 3;
    const int bn  = (g & 7) * 4 + (idx >> 4);   // 0..31
    const int bm  = idx & 15;                   // 0..15

    // B staging: 2 gload_lds/thread/kt; slot s = c*256 + tid
    const int8_t* gB0; const int8_t* gB1;
    uint32_t lo0, lo1;
    {
        int s0 = tid;
        gB0 = Bf + ((size_t)(bn * 4 + (s0 >> 7)) * KC + ((s0 >> 6) & 1)) * 1024 + (s0 & 63) * 16;
        lo0 = (uint32_t)s0 * 16;
        int s1 = tid + 256;
        gB1 = Bf + ((size_t)(bn * 4 + (s1 >> 7)) * KC + ((s1 >> 6) & 1)) * 1024 + (s1 & 63) * 16;
        lo1 = (uint32_t)s1 * 16;
    }

    // A source: rows (bm*4 + wr*2 + i), kc slabs; per-kt advance 2048B
    const int8_t* gA = Af + ((size_t)(bm * 4 + wr * 2) * KC) * 1024 + lane * 16;

    v16i acc[2][2];
    #pragma unroll
    for (int i = 0; i < 2; ++i)
        #pragma unroll
        for (int j = 0; j < 2; ++j) acc[i][j] = {};

    // prologue: A(0) -> bankA; B(0)->buf0; B(1)->buf1
    v4i aA0 = *(const v4i*)(gA);
    v4i aA1 = *(const v4i*)(gA + 1024);
    v4i aA2 = *(const v4i*)(gA + 131072);
    v4i aA3 = *(const v4i*)(gA + 132096);
    gload_lds16(gB0, lds + lo0);         gB0 += 2048;
    gload_lds16(gB1, lds + lo1);         gB1 += 2048;
    gload_lds16(gB0, lds + BUFSZ + lo0); gB0 += 2048;
    gload_lds16(gB1, lds + BUFSZ + lo1); gB1 += 2048;
    v4i aB0{}, aB1{}, aB2{}, aB3{};

    uint32_t bo = 0;

    auto kt_body = [&](int kt, v4i& AR0, v4i& AR1, v4i& AR2, v4i& AR3,
                               v4i& AW0, v4i& AW1, v4i& AW2, v4i& AW3) {
        // lead: collective "B(kt) landed (+ A(kt) in regs)"; counted, never 0 mid-loop
        if (kt + 1 < NKT) asm volatile("s_waitcnt vmcnt(2)" ::: "memory");
        else              asm volatile("s_waitcnt vmcnt(0)" ::: "memory");
        __builtin_amdgcn_sched_barrier(0);
        __builtin_amdgcn_s_barrier();
        __builtin_amdgcn_sched_barrier(0);

        const uint32_t sbo = (bo >= BUFSZ) ? (bo - BUFSZ) : (2u * BUFSZ);
        const int8_t* Bb = lds + bo + wc * 4096 + lane * 16;

        // phase 0 (kc=0)
        v4i bf00 = *(const v4i*)(Bb + 0);
        v4i bf10 = *(const v4i*)(Bb + 2048);
        __builtin_amdgcn_s_setprio(1);
        acc[0][0] = __builtin_amdgcn_mfma_i32_32x32x32_i8(AR0, bf00, acc[0][0], 0, 0, 0);
        acc[0][1] = __builtin_amdgcn_mfma_i32_32x32x32_i8(AR0, bf10, acc[0][1], 0, 0, 0);
        acc[1][0] = __builtin_amdgcn_mfma_i32_32x32x32_i8(AR2, bf00, acc[1][0], 0, 0, 0);
        acc[1][1] = __builtin_amdgcn_mfma_i32_32x32x32_i8(AR2, bf10, acc[1][1], 0, 0, 0);
        __builtin_amdgcn_s_setprio(0);

        // issue A(kt+1) into the other bank (consumed next kt; compiler waits)
        if (kt + 1 < NKT) {
            const int8_t* ga = gA + (kt + 1) * 2048;
            AW0 = *(const v4i*)(ga);
            AW1 = *(const v4i*)(ga + 1024);
            AW2 = *(const v4i*)(ga + 131072);
            AW3 = *(const v4i*)(ga + 132096);
            __builtin_amdgcn_sched_barrier(0);   // pin: A-issues precede B-DMA issues
        }
        // issue B(kt+2) into ring slot whose reads finished before this kt's lead
        if (kt + 2 < NKT) {
            gload_lds16(gB0, lds + sbo + lo0); gB0 += 2048;
            gload_lds16(gB1, lds + sbo + lo1); gB1 += 2048;
        }

        // phase 1 (kc=1)
        v4i bf01 = *(const v4i*)(Bb + 1024);
        v4i bf11 = *(const v4i*)(Bb + 3072);
        __builtin_amdgcn_s_setprio(1);
        acc[0][0] = __builtin_amdgcn_mfma_i32_32x32x32_i8(AR1, bf01, acc[0][0], 0, 0, 0);
        acc[0][1] = __builtin_amdgcn_mfma_i32_32x32x32_i8(AR1, bf11, acc[0][1], 0, 0, 0);
        acc[1][0] = __builtin_amdgcn_mfma_i32_32x32x32_i8(AR3, bf01, acc[1][0], 0, 0, 0);
        acc[1][1] = __builtin_amdgcn_mfma_i32_32x32x32_i8(AR3, bf11, acc[1][1], 0, 0, 0);
        __builtin_amdgcn_s_setprio(0);

        bo = (bo == 2u * BUFSZ) ? 0u : bo + BUFSZ;
    };

    #pragma unroll 1
    for (int kt = 0; kt < NKT; kt += 2) {
        kt_body(kt,     aA0, aA1, aA2, aA3, aB0, aB1, aB2, aB3);
        kt_body(kt + 1, aB0, aB1, aB2, aB3, aA0, aA1, aA2, aA3);
    }

    // ---- epilogue: threshold -> +-1 bytes -> LDS transpose -> Act slabs ----
    __syncthreads();
    const int thr = *thr_ptr;
    int8_t* bits = lds;                         // [128][144] = 18KB <= 24KB
    #pragma unroll
    for (int i = 0; i < 2; ++i)
        #pragma unroll
        for (int j = 0; j < 2; ++j) {
            int dimb = wr * 64 + i * 32 + 4 * (lane >> 5);
            int gcl  = wc * 64 + j * 32 + (lane & 31);
            #pragma unroll
            for (int reg = 0; reg < 16; ++reg) {
                int dl = dimb + (reg & 3) + 8 * (reg >> 2);
                int match = (4096 + acc[i][j][reg]) >> 1;
                bits[dl * 144 + gcl] = (match >= thr) ? (int8_t)1 : (int8_t)-1;
            }
        }
    __syncthreads();
    // 16 slabs (4 dimblk x 4 kc) x 1KB; 16 threads/slab, 4 lanes each
    const int s    = tid >> 4;                  // 0..15
    const int dblk = s >> 2, kcl = s & 3;
    const int l0   = (tid & 15) * 4;
    int8_t* dst = actf + ((size_t)(bm * 4 + dblk) * KC + bn * 4 + kcl) * 1024;
    #pragma unroll
    for (int li = 0; li < 4; ++li) {
        int l = l0 + li;
        uint4 v = *(const uint4*)(bits + (dblk * 32 + (l & 31)) * 144
                                       + kcl * 32 + (l >> 5) * 16);
        *(uint4*)(dst + l * 16) = v;
    }
}

// ================= layer 2: round-9 proven kernel (128x64 tiles) ============
template<int WN>
__global__ __launch_bounds__(256, 1)
void bnn_mfma2(const int8_t* __restrict__ Af,
               const int8_t* __restrict__ Bf,
               int* __restrict__ out, int Nout)
{
    constexpr int KC     = 128;
    constexpr int NKT    = 64;
    constexpr int NBB    = 2 * WN;
    constexpr int ASLOTS = 512;
    constexpr int BSLOTS = 128 * NBB;
    constexpr int SLOTS  = ASLOTS + BSLOTS;
    constexpr int NLD    = SLOTS / 256;
    constexpr uint32_t BUFSZ = (uint32_t)SLOTS * 16;

    __shared__ int8_t lds[3][SLOTS * 16];

    const int tid  = threadIdx.x;
    const int lane = tid & 63;
    const int wv   = tid >> 6;
    const int wr   = wv >> 1, wc = wv & 1;

    const int g   = blockIdx.x;
    const int idx = g >> 3;
    const int bn  = (g & 7) * 2 + (idx >> 4);
    const int bm  = idx & 15;

    const int8_t* gsrc[NLD];
    uint32_t ldoff[NLD];
    #pragma unroll
    for (int i = 0; i < NLD; ++i) {
        int sbase = wv * 64 + 256 * i;
        ldoff[i] = (uint32_t)sbase * 16;
        const int8_t* base;
        if (sbase < ASLOTS) {
            int R = sbase >> 7, C = (sbase >> 6) & 1;
            base = Af + ((size_t)(bm * 4 + R) * KC + C) * 1024;
        } else {
            int s = sbase - ASLOTS;
            int R = s >> 7, C = (s >> 6) & 1;
            base = Bf + ((size_t)(bn * NBB + R) * KC + C) * 1024;
        }
        gsrc[i] = base + lane * 16;
    }

    auto stage = [&](int buf) {
        #pragma unroll
        for (int i = 0; i < NLD; ++i) {
            gload_lds16(gsrc[i], (int8_t*)lds + (uint32_t)buf * BUFSZ + ldoff[i]);
            gsrc[i] += 2048;
        }
    };

    v16i acc[2][WN];
    #pragma unroll
    for (int i = 0; i < 2; ++i)
        #pragma unroll
        for (int j = 0; j < WN; ++j) acc[i][j] = {};

    stage(0);
    stage(1);

    int cur = 0, nxt = 2;
    #pragma unroll 1
    for (int kt = 0; kt < NKT; ++kt) {
        if (kt < NKT - 1) asm volatile("s_waitcnt vmcnt(3)" ::: "memory");
        else              asm volatile("s_waitcnt vmcnt(0)" ::: "memory");
        __builtin_amdgcn_sched_barrier(0);
        __builtin_amdgcn_s_barrier();
        __builtin_amdgcn_sched_barrier(0);

        if (kt < NKT - 2) {
            stage(nxt);
            nxt = (nxt == 2) ? 0 : nxt + 1;
        }

        const int8_t* Al = lds[cur];
        const int8_t* Bl = lds[cur] + ASLOTS * 16;
        #pragma unroll
        for (int kc = 0; kc < 2; ++kc) {
            v4i af[2], bf[WN];
            #pragma unroll
            for (int i = 0; i < 2; ++i)
                af[i] = *(const v4i*)(Al + (((wr * 2 + i) * 2 + kc) * 64 + lane) * 16);
            #pragma unroll
            for (int j = 0; j < WN; ++j)
                bf[j] = *(const v4i*)(Bl + (((wc * WN + j) * 2 + kc) * 64 + lane) * 16);
            #pragma unroll
            for (int i = 0; i < 2; ++i)
                #pragma unroll
                for (int j = 0; j < WN; ++j)
                    acc[i][j] = __builtin_amdgcn_mfma_i32_32x32x32_i8(af[i], bf[j], acc[i][j], 0, 0, 0);
        }
        cur = (cur == 2) ? 0 : cur + 1;
    }

    #pragma unroll
    for (int i = 0; i < 2; ++i)
        #pragma unroll
        for (int j = 0; j < WN; ++j) {
            int gc = bn * (64 * WN) + wc * (32 * WN) + j * 32 + (lane & 31);
            #pragma unroll
            for (int reg = 0; reg < 16; ++reg) {
                int gr = bm * 128 + wr * 64 + i * 32
                       + (reg & 3) + 8 * (reg >> 2) + 4 * (lane >> 5);
                out[(size_t)gr * Nout + gc] = (4096 + acc[i][j][reg]) >> 1;
            }
        }
}

// ============================ launcher ============================
extern "C" void kernel_launch(void* const* d_in, const int* in_sizes, int n_in,
                              void* d_out, int out_size, void* d_ws, size_t ws_size,
                              hipStream_t stream) {
    const float* x   = (const float*)d_in[0];
    const int*   w1  = (const int*)d_in[1];
    const int*   w2  = (const int*)d_in[2];
    const int*   thr = (const int*)d_in[3];
    int* out = (int*)d_out;

    const int B = 2048, IN = 4096, H = 4096, OUT = 1024;
    uint8_t* ws = (uint8_t*)d_ws;

    // Af 8MB | W1f 16MB | W2f 4MB | Act 8MB
    int8_t* Af  = (int8_t*)(ws);
    int8_t* W1f = (int8_t*)(ws + ((size_t)8  << 20));
    int8_t* W2f = (int8_t*)(ws + ((size_t)24 << 20));
    int8_t* Act = (int8_t*)(ws + ((size_t)28 << 20));

    pack_frag<float, true ><<<dim3(IN / 1024, B   / 32), 512, 0, stream>>>(x,  Af,  IN);
    pack_frag<int,   false><<<dim3(IN / 1024, H   / 32), 512, 0, stream>>>(w1, W1f, IN);
    pack_frag<int,   false><<<dim3(H  / 1024, OUT / 32), 512, 0, stream>>>(w2, W2f, H);

    bnn_l1_areg<<<512, 256, 0, stream>>>(Af, W1f, thr, Act);                    // 128x128 tiles
    bnn_mfma2<1><<<256, 256, 0, stream>>>(Act, W2f, out, OUT);                  // 128x64 tiles
}